// Round 4
// baseline (309.087 us; speedup 1.0000x reference)
//
#include <hip/hip_runtime.h>
#include <hip/hip_bf16.h>

#define BS 32
#define NBC 33

typedef unsigned long long ull;
typedef __attribute__((ext_vector_type(8))) __bf16 bf16x8;
typedef __attribute__((ext_vector_type(4))) float f32x4;

__device__ __forceinline__ unsigned short f2b(float f) {
    __hip_bfloat16 h = __float2bfloat16(f);
    return *reinterpret_cast<unsigned short*>(&h);
}
__device__ __forceinline__ float b2f(unsigned short u) {
    union { unsigned int i; float f; } x; x.i = ((unsigned int)u) << 16; return x.f;
}
#define LD8(p) (*reinterpret_cast<const bf16x8*>(p))

// ---- zero the id table (faster than hipMemsetAsync for 34.6 MB) ----
__global__ void zero_kernel(uint4* __restrict__ p, int n4) {
    int stride = gridDim.x * blockDim.x;
    for (int i = blockIdx.x * blockDim.x + threadIdx.x; i < n4; i += stride)
        p[i] = make_uint4(0u, 0u, 0u, 0u);
}

// ---- pass 1: last-edge-wins scatter, 32-bit winner id (atomicMax over edge id) ----
__global__ void edge_scatter_kernel(const int* __restrict__ rows,
                                    const int* __restrict__ cols,
                                    unsigned* __restrict__ tbl, int E) {
    int base = (blockIdx.x * 256 + threadIdx.x) * 4;
    if (base >= E) return;
    if (base + 4 <= E) {
        int4 r4 = *reinterpret_cast<const int4*>(rows + base);
        int4 c4 = *reinterpret_cast<const int4*>(cols + base);
        int rr[4] = {r4.x, r4.y, r4.z, r4.w};
        int cc[4] = {c4.x, c4.y, c4.z, c4.w};
        #pragma unroll
        for (int k = 0; k < 4; ++k) {
            int r = rr[k], c = cc[k];
            if ((r >> 5) == (c >> 5) && r != c)
                atomicMax(&tbl[((size_t)(r >> 5) * BS + (r & 31)) * NBC + (c & 31)],
                          (unsigned)(base + k + 1));
        }
    } else {
        for (int e = base; e < E && e < base + 4; ++e) {
            int r = rows[e], c = cols[e];
            if ((r >> 5) == (c >> 5) && r != c)
                atomicMax(&tbl[((size_t)(r >> 5) * BS + (r & 31)) * NBC + (c & 31)],
                          (unsigned)(e + 1));
        }
    }
}

// ---- pass 2: repack weights into MFMA B-fragment order (per-head tile grouping) ----
// qkv frag F = ((w*6+s)*4+ks): wave w; s=0,1 q / 2,3 k / 4,5 v tiles. 512 bf16/frag.
__global__ void prepack_kernel(const float* __restrict__ qkv_w,
                               const float* __restrict__ proj_w,
                               unsigned short* __restrict__ wq,
                               unsigned short* __restrict__ wp) {
    int tid = blockIdx.x * 256 + threadIdx.x;   // 0..65535
    int f = tid >> 9, lane = (tid >> 3) & 63, j = tid & 7;
    int ks = f & 3;
    int kk = ks * 32 + (lane >> 4) * 8 + j;
    int nn = lane & 15;
    if (f < 96) {
        int t = f >> 2;                 // 0..23
        int w = t / 6, s = t % 6;
        int g = (s < 2) ? (2 * w + s) : (s < 4) ? (8 + 2 * w + (s - 2)) : (16 + 2 * w + (s - 4));
        wq[tid] = f2b(qkv_w[kk * 384 + g * 16 + nn]);
    } else {
        int f2 = f - 96;                // proj frag = nt_global*4+ks
        wp[f2 * 512 + lane * 8 + j] = f2b(proj_w[kk * 128 + (f2 >> 2) * 16 + nn]);
    }
}

// ---- main fused kernel: one 4-wave WG per block; wave w owns head w end-to-end ----
__global__ __launch_bounds__(256)
void block_attn_kernel(const float* __restrict__ x,
                       const unsigned* __restrict__ tbl,
                       const float* __restrict__ vals,
                       const unsigned short* __restrict__ wq,
                       const unsigned short* __restrict__ wp,
                       const float* __restrict__ qkv_b,
                       const float* __restrict__ proj_b,
                       const float* __restrict__ gate_w,
                       const float* __restrict__ gate_b,
                       float* __restrict__ out) {
    __shared__ __align__(16) unsigned short qs[4][32][40];   // Q -> P -> attn-out
    __shared__ __align__(16) unsigned short ksm[4][34][40];  // K rows + mean(32) + zero(33)
    __shared__ __align__(16) unsigned short vT[4][32][40];   // V^T [dim][kvrow]; col 32 = mean
    __shared__ float pcol[4][32];                            // P column 32 (block node), fp32

    const int b = blockIdx.x, t = threadIdx.x;
    const int w = t >> 6, l = t & 63, g16 = l >> 4, c16 = l & 15;
    const f32x4 z4 = {0.f, 0.f, 0.f, 0.f};
    const float NEG = -1.0e30f;

    if (l < 32) ksm[w][33][l] = 0;   // zero pad row (wave-private use)

    // ---- edge bias wb per score slot; sentinel NEG = masked-out ----
    // slot 0: j=c16; slot 1: j=16+c16; slot 2: block-node col (real only at c16==0)
    float wb[2][4][3];
    {
        const unsigned* tb = tbl + (size_t)b * (BS * NBC);
        unsigned idr[2][4][2];
        #pragma unroll
        for (int mt = 0; mt < 2; ++mt)
            #pragma unroll
            for (int r = 0; r < 4; ++r) {
                const int i = 16 * mt + 4 * g16 + r;
                #pragma unroll
                for (int nt = 0; nt < 2; ++nt)
                    idr[mt][r][nt] = tb[i * NBC + 16 * nt + c16];
            }
        #pragma unroll
        for (int mt = 0; mt < 2; ++mt)
            #pragma unroll
            for (int r = 0; r < 4; ++r) {
                const int i = 16 * mt + 4 * g16 + r;
                #pragma unroll
                for (int nt = 0; nt < 2; ++nt) {
                    const int j = 16 * nt + c16;
                    const unsigned id = idr[mt][r][nt];
                    wb[mt][r][nt] = (j == i) ? 1.f : (id ? vals[id - 1] : NEG);
                }
                wb[mt][r][2] = (c16 == 0) ? 1.f : NEG;
            }
    }

    // ---- x A-fragments straight from global (fp32 -> bf16) ----
    bf16x8 a[2][4];
    const float* xb = x + (size_t)b * (BS * 128);
    #pragma unroll
    for (int mt = 0; mt < 2; ++mt)
        #pragma unroll
        for (int ks = 0; ks < 4; ++ks) {
            const float* p = xb + (c16 + 16 * mt) * 128 + ks * 32 + g16 * 8;
            float4 f0 = *reinterpret_cast<const float4*>(p);
            float4 f1 = *reinterpret_cast<const float4*>(p + 4);
            union { bf16x8 v; unsigned short u[8]; } cv;
            cv.u[0] = f2b(f0.x); cv.u[1] = f2b(f0.y); cv.u[2] = f2b(f0.z); cv.u[3] = f2b(f0.w);
            cv.u[4] = f2b(f1.x); cv.u[5] = f2b(f1.y); cv.u[6] = f2b(f1.z); cv.u[7] = f2b(f1.w);
            a[mt][ks] = cv.v;
        }

    // ---- QKV for head w: 6 n-tiles (q0,q1,k0,k1,v0,v1), K=128 ----
    {
        const unsigned short* wqs = wq + (size_t)(w * 24) * 512 + l * 8;
        #pragma unroll
        for (int s = 0; s < 6; ++s) {
            bf16x8 bn[4];
            #pragma unroll
            for (int ks = 0; ks < 4; ++ks) bn[ks] = LD8(wqs + (s * 4 + ks) * 512);
            f32x4 acc0 = z4, acc1 = z4;
            #pragma unroll
            for (int ks = 0; ks < 4; ++ks) {
                acc0 = __builtin_amdgcn_mfma_f32_16x16x32_bf16(a[0][ks], bn[ks], acc0, 0, 0, 0);
                acc1 = __builtin_amdgcn_mfma_f32_16x16x32_bf16(a[1][ks], bn[ks], acc1, 0, 0, 0);
            }
            const float bias = qkv_b[(s >> 1) * 128 + 32 * w + 16 * (s & 1) + c16];
            const int cc = 16 * (s & 1) + c16;
            if (s < 2) {
                #pragma unroll
                for (int r = 0; r < 4; ++r) {
                    qs[w][4 * g16 + r][cc]      = f2b(acc0[r] + bias);
                    qs[w][16 + 4 * g16 + r][cc] = f2b(acc1[r] + bias);
                }
            } else {
                float csum = acc0[0] + acc0[1] + acc0[2] + acc0[3]
                           + acc1[0] + acc1[1] + acc1[2] + acc1[3];
                csum += __shfl_xor(csum, 16, 64);
                csum += __shfl_xor(csum, 32, 64);
                const float meanv = csum * (1.f / 32.f) + bias;
                if (s < 4) {
                    #pragma unroll
                    for (int r = 0; r < 4; ++r) {
                        ksm[w][4 * g16 + r][cc]      = f2b(acc0[r] + bias);
                        ksm[w][16 + 4 * g16 + r][cc] = f2b(acc1[r] + bias);
                    }
                    if (g16 == 0) ksm[w][32][cc] = f2b(meanv);
                } else {
                    #pragma unroll
                    for (int r = 0; r < 4; ++r) {
                        vT[w][cc][4 * g16 + r]      = f2b(acc0[r] + bias);
                        vT[w][cc][16 + 4 * g16 + r] = f2b(acc1[r] + bias);
                    }
                    if (g16 == 0) vT[w][cc][32] = f2b(meanv);
                }
            }
        }
    }
    __syncthreads();   // drain QKV staging

    // ---- QK^T (K=32, one k-step per n-tile) ----
    f32x4 s[2][3];
    {
        bf16x8 aq0 = LD8(&qs[w][c16][g16 * 8]);
        bf16x8 aq1 = LD8(&qs[w][16 + c16][g16 * 8]);
        bf16x8 bk0 = LD8(&ksm[w][c16][g16 * 8]);
        bf16x8 bk1 = LD8(&ksm[w][16 + c16][g16 * 8]);
        const int n2 = (c16 == 0) ? 32 : 33;
        bf16x8 bk2 = LD8(&ksm[w][n2][g16 * 8]);
        s[0][0] = __builtin_amdgcn_mfma_f32_16x16x32_bf16(aq0, bk0, z4, 0, 0, 0);
        s[0][1] = __builtin_amdgcn_mfma_f32_16x16x32_bf16(aq0, bk1, z4, 0, 0, 0);
        s[0][2] = __builtin_amdgcn_mfma_f32_16x16x32_bf16(aq0, bk2, z4, 0, 0, 0);
        s[1][0] = __builtin_amdgcn_mfma_f32_16x16x32_bf16(aq1, bk0, z4, 0, 0, 0);
        s[1][1] = __builtin_amdgcn_mfma_f32_16x16x32_bf16(aq1, bk1, z4, 0, 0, 0);
        s[1][2] = __builtin_amdgcn_mfma_f32_16x16x32_bf16(aq1, bk2, z4, 0, 0, 0);
    }

    // ---- softmax with max-subtraction (overflow-proof) + gate; stage P ----
    {
        const float scale = 0.17677669529663687f;   // 32^-0.5
        const float gwh = gate_w[w], gbh = gate_b[w];
        #pragma unroll
        for (int mt = 0; mt < 2; ++mt)
            #pragma unroll
            for (int r = 0; r < 4; ++r) {
                const int i = 16 * mt + 4 * g16 + r;
                float sc[3];
                #pragma unroll
                for (int k = 0; k < 3; ++k) sc[k] = s[mt][k][r] * scale + wb[mt][r][k];
                float mx = fmaxf(fmaxf(sc[0], sc[1]), sc[2]);
                mx = fmaxf(mx, __shfl_xor(mx, 1, 64));
                mx = fmaxf(mx, __shfl_xor(mx, 2, 64));
                mx = fmaxf(mx, __shfl_xor(mx, 4, 64));
                mx = fmaxf(mx, __shfl_xor(mx, 8, 64));
                float e0 = __expf(sc[0] - mx), e1 = __expf(sc[1] - mx), e2 = __expf(sc[2] - mx);
                float sum = e0 + e1 + e2;
                sum += __shfl_xor(sum, 1, 64);
                sum += __shfl_xor(sum, 2, 64);
                sum += __shfl_xor(sum, 4, 64);
                sum += __shfl_xor(sum, 8, 64);
                const float inv = __builtin_amdgcn_rcpf(sum);
                float gt0 = (wb[mt][r][0] > -1.0e29f) ? wb[mt][r][0] * gwh + gbh : 0.f;
                float gt1 = (wb[mt][r][1] > -1.0e29f) ? wb[mt][r][1] * gwh + gbh : 0.f;
                float gt2 = (wb[mt][r][2] > -1.0e29f) ? gwh + gbh : 0.f;
                qs[w][i][c16]      = f2b(e0 * inv + gt0);
                qs[w][i][16 + c16] = f2b(e1 * inv + gt1);
                if (c16 == 0) pcol[w][i] = e2 * inv + gt2;
            }
    }
    __syncthreads();   // drain P staging

    // ---- PV (rows 0-31 via MFMA, block-node row via rank-1) -> attn-out into qs ----
    {
        bf16x8 ap0 = LD8(&qs[w][c16][g16 * 8]);
        bf16x8 ap1 = LD8(&qs[w][16 + c16][g16 * 8]);
        f32x4 o[2][2];
        #pragma unroll
        for (int nt = 0; nt < 2; ++nt) {
            bf16x8 bv = LD8(&vT[w][16 * nt + c16][g16 * 8]);
            o[0][nt] = __builtin_amdgcn_mfma_f32_16x16x32_bf16(ap0, bv, z4, 0, 0, 0);
            o[1][nt] = __builtin_amdgcn_mfma_f32_16x16x32_bf16(ap1, bv, z4, 0, 0, 0);
        }
        #pragma unroll
        for (int nt = 0; nt < 2; ++nt) {
            const float vm = b2f(vT[w][16 * nt + c16][32]);
            #pragma unroll
            for (int mt = 0; mt < 2; ++mt)
                #pragma unroll
                for (int r = 0; r < 4; ++r)
                    o[mt][nt][r] += pcol[w][16 * mt + 4 * g16 + r] * vm;
        }
        #pragma unroll
        for (int mt = 0; mt < 2; ++mt)
            #pragma unroll
            for (int nt = 0; nt < 2; ++nt)
                #pragma unroll
                for (int r = 0; r < 4; ++r)
                    qs[w][16 * mt + 4 * g16 + r][16 * nt + c16] = f2b(o[mt][nt][r]);
    }
    __syncthreads();   // all heads' attn-out ready

    // ---- projection: k-step h reads head-h buffer; wave w owns out cols [32w,32w+32) ----
    {
        bf16x8 aa[2][4];
        #pragma unroll
        for (int mt = 0; mt < 2; ++mt)
            #pragma unroll
            for (int h = 0; h < 4; ++h)
                aa[mt][h] = LD8(&qs[h][c16 + 16 * mt][g16 * 8]);
        f32x4 po[2][2];
        po[0][0] = z4; po[0][1] = z4; po[1][0] = z4; po[1][1] = z4;
        const unsigned short* wps = wp + l * 8;
        #pragma unroll
        for (int nt = 0; nt < 2; ++nt)
            #pragma unroll
            for (int h = 0; h < 4; ++h) {
                bf16x8 bw = LD8(wps + (size_t)((2 * w + nt) * 4 + h) * 512);
                po[0][nt] = __builtin_amdgcn_mfma_f32_16x16x32_bf16(aa[0][h], bw, po[0][nt], 0, 0, 0);
                po[1][nt] = __builtin_amdgcn_mfma_f32_16x16x32_bf16(aa[1][h], bw, po[1][nt], 0, 0, 0);
            }
        float* ob = out + (size_t)b * (BS * 128);
        #pragma unroll
        for (int nt = 0; nt < 2; ++nt) {
            const int col = 32 * w + 16 * nt + c16;
            const float pbv = proj_b[col];
            #pragma unroll
            for (int mt = 0; mt < 2; ++mt)
                #pragma unroll
                for (int r = 0; r < 4; ++r)
                    ob[(size_t)(16 * mt + 4 * g16 + r) * 128 + col] = po[mt][nt][r] + pbv;
        }
    }
}

extern "C" void kernel_launch(void* const* d_in, const int* in_sizes, int n_in,
                              void* d_out, int out_size, void* d_ws, size_t ws_size,
                              hipStream_t stream) {
    const float* x      = (const float*)d_in[0];
    const int*   ei     = (const int*)d_in[1];
    const float* ev     = (const float*)d_in[2];
    // d_in[3] = positions: unused by the reference output
    const float* qkv_w  = (const float*)d_in[4];
    const float* qkv_b  = (const float*)d_in[5];
    const float* proj_w = (const float*)d_in[6];
    const float* proj_b = (const float*)d_in[7];
    const float* gate_w = (const float*)d_in[8];
    const float* gate_b = (const float*)d_in[9];
    float* out = (float*)d_out;

    const int E  = in_sizes[2];
    const int N  = in_sizes[0] / 128;
    const int nb = N / BS;

    unsigned* tbl = (unsigned*)d_ws;
    size_t twords = (size_t)nb * BS * NBC;
    size_t tbytes = (twords * sizeof(unsigned) + 255) & ~(size_t)255;
    unsigned short* wqp = (unsigned short*)((char*)d_ws + tbytes);
    unsigned short* wpp = wqp + 96 * 512;

    zero_kernel<<<2048, 256, 0, stream>>>((uint4*)tbl, (int)(twords / 4));
    prepack_kernel<<<256, 256, 0, stream>>>(qkv_w, proj_w, wqp, wpp);
    edge_scatter_kernel<<<((E + 3) / 4 + 255) / 256, 256, 0, stream>>>(ei, ei + E, tbl, E);
    block_attn_kernel<<<nb, 256, 0, stream>>>(x, tbl, ev, wqp, wpp, qkv_b, proj_b,
                                              gate_w, gate_b, out);
}

// Round 5
// 270.771 us; speedup vs baseline: 1.1415x; 1.1415x over previous
//
#include <hip/hip_runtime.h>
#include <hip/hip_bf16.h>

#define BS 32
#define NBC 33

typedef unsigned long long ull;
typedef __attribute__((ext_vector_type(8))) __bf16 bf16x8;
typedef __attribute__((ext_vector_type(4))) float f32x4;
typedef __attribute__((ext_vector_type(4))) unsigned short us4;

__device__ __forceinline__ unsigned short f2b(float f) {
    __hip_bfloat16 h = __float2bfloat16(f);
    return *reinterpret_cast<unsigned short*>(&h);
}
__device__ __forceinline__ float b2f(unsigned short u) {
    union { unsigned int i; float f; } x; x.i = ((unsigned int)u) << 16; return x.f;
}
#define LD8(p) (*reinterpret_cast<const bf16x8*>(p))

// ---- fused: zero the id table (blocks 0..ZB-1) + repack weights (blocks ZB..ZB+255) ----
#define ZB 2048
__global__ void zero_prepack_kernel(uint4* __restrict__ tbl4, int n4,
                                    const float* __restrict__ qkv_w,
                                    const float* __restrict__ proj_w,
                                    unsigned short* __restrict__ wq,
                                    unsigned short* __restrict__ wp) {
    if (blockIdx.x < ZB) {
        int stride = ZB * 256;
        for (int i = blockIdx.x * 256 + threadIdx.x; i < n4; i += stride)
            tbl4[i] = make_uint4(0u, 0u, 0u, 0u);
    } else {
        int tid = (blockIdx.x - ZB) * 256 + threadIdx.x;   // 0..65535
        int f = tid >> 9, lane = (tid >> 3) & 63, j = tid & 7;
        int ks = f & 3;
        int kk = ks * 32 + (lane >> 4) * 8 + j;
        int nn = lane & 15;
        if (f < 96) {
            int t = f >> 2;                 // 0..23
            int w = t / 6, s = t % 6;
            int g = (s < 2) ? (2 * w + s) : (s < 4) ? (8 + 2 * w + (s - 2)) : (16 + 2 * w + (s - 4));
            wq[tid] = f2b(qkv_w[kk * 384 + g * 16 + nn]);
        } else {
            int f2 = f - 96;                // proj frag = nt_global*4+ks
            wp[f2 * 512 + lane * 8 + j] = f2b(proj_w[kk * 128 + (f2 >> 2) * 16 + nn]);
        }
    }
}

// ---- pass 1: last-edge-wins scatter, 32-bit winner id (atomicMax over edge id) ----
__global__ void edge_scatter_kernel(const int* __restrict__ rows,
                                    const int* __restrict__ cols,
                                    unsigned* __restrict__ tbl, int E) {
    int base = (blockIdx.x * 256 + threadIdx.x) * 4;
    if (base >= E) return;
    if (base + 4 <= E) {
        int4 r4 = *reinterpret_cast<const int4*>(rows + base);
        int4 c4 = *reinterpret_cast<const int4*>(cols + base);
        int rr[4] = {r4.x, r4.y, r4.z, r4.w};
        int cc[4] = {c4.x, c4.y, c4.z, c4.w};
        #pragma unroll
        for (int k = 0; k < 4; ++k) {
            int r = rr[k], c = cc[k];
            if ((r >> 5) == (c >> 5) && r != c)
                atomicMax(&tbl[((size_t)(r >> 5) * BS + (r & 31)) * NBC + (c & 31)],
                          (unsigned)(base + k + 1));
        }
    } else {
        for (int e = base; e < E && e < base + 4; ++e) {
            int r = rows[e], c = cols[e];
            if ((r >> 5) == (c >> 5) && r != c)
                atomicMax(&tbl[((size_t)(r >> 5) * BS + (r & 31)) * NBC + (c & 31)],
                          (unsigned)(e + 1));
        }
    }
}

// ---- main fused kernel: one 4-wave WG per block; wave w owns head w end-to-end ----
__global__ __launch_bounds__(256)
void block_attn_kernel(const float* __restrict__ x,
                       const unsigned* __restrict__ tbl,
                       const float* __restrict__ vals,
                       const unsigned short* __restrict__ wq,
                       const unsigned short* __restrict__ wp,
                       const float* __restrict__ qkv_b,
                       const float* __restrict__ proj_b,
                       const float* __restrict__ gate_w,
                       const float* __restrict__ gate_b,
                       float* __restrict__ out) {
    __shared__ __align__(16) unsigned short xs[32][136];     // x staged bf16 (stride 272B)
    __shared__ __align__(16) unsigned short qs[4][32][40];   // Q -> P -> attn-out
    __shared__ __align__(16) unsigned short ksm[4][34][40];  // K rows + mean(32) + zero(33)
    __shared__ __align__(16) unsigned short vT[4][32][40];   // V^T [dim][kvrow]; col 32 = mean
    __shared__ float pcol[4][32];                            // P column 32 (block node), fp32

    const int b = blockIdx.x, t = threadIdx.x;
    const int w = t >> 6, l = t & 63, g16 = l >> 4, c16 = l & 15;
    const f32x4 z4 = {0.f, 0.f, 0.f, 0.f};
    const float NEG = -1.0e30f;

    // ---- phase 0: stage x block (coalesced float4 -> bf16 LDS) ----
    const float* xb = x + (size_t)b * (BS * 128);
    #pragma unroll
    for (int it = 0; it < 4; ++it) {
        int idx = (t + it * 256) * 4;
        float4 v = *reinterpret_cast<const float4*>(xb + idx);
        us4 u; u.x = f2b(v.x); u.y = f2b(v.y); u.z = f2b(v.z); u.w = f2b(v.w);
        *reinterpret_cast<us4*>(&xs[idx >> 7][idx & 127]) = u;
    }
    if (l < 32) ksm[w][33][l] = 0;   // zero pad row (wave-private use)

    // ---- edge bias wb per score slot (issued early; hides under QKV MFMAs) ----
    // slot 0: j=c16; slot 1: j=16+c16; slot 2: block-node col (real only at c16==0)
    float wb[2][4][3];
    {
        const unsigned* tb = tbl + (size_t)b * (BS * NBC);
        unsigned idr[2][4][2];
        #pragma unroll
        for (int mt = 0; mt < 2; ++mt)
            #pragma unroll
            for (int r = 0; r < 4; ++r) {
                const int i = 16 * mt + 4 * g16 + r;
                #pragma unroll
                for (int nt = 0; nt < 2; ++nt)
                    idr[mt][r][nt] = tb[i * NBC + 16 * nt + c16];
            }
        #pragma unroll
        for (int mt = 0; mt < 2; ++mt)
            #pragma unroll
            for (int r = 0; r < 4; ++r) {
                const int i = 16 * mt + 4 * g16 + r;
                #pragma unroll
                for (int nt = 0; nt < 2; ++nt) {
                    const int j = 16 * nt + c16;
                    const unsigned id = idr[mt][r][nt];
                    wb[mt][r][nt] = (j == i) ? 1.f : (id ? vals[id - 1] : NEG);
                }
                wb[mt][r][2] = (c16 == 0) ? 1.f : NEG;
            }
    }
    __syncthreads();   // x staged

    // ---- A-fragments from LDS ----
    bf16x8 a[2][4];
    #pragma unroll
    for (int mt = 0; mt < 2; ++mt)
        #pragma unroll
        for (int ks = 0; ks < 4; ++ks)
            a[mt][ks] = LD8(&xs[c16 + 16 * mt][ks * 32 + g16 * 8]);

    // ---- QKV for head w: 6 n-tiles (q0,q1,k0,k1,v0,v1), K=128 ----
    {
        const unsigned short* wqs = wq + (size_t)(w * 24) * 512 + l * 8;
        #pragma unroll
        for (int s = 0; s < 6; ++s) {
            bf16x8 bn[4];
            #pragma unroll
            for (int ks = 0; ks < 4; ++ks) bn[ks] = LD8(wqs + (s * 4 + ks) * 512);
            f32x4 acc0 = z4, acc1 = z4;
            #pragma unroll
            for (int ks = 0; ks < 4; ++ks) {
                acc0 = __builtin_amdgcn_mfma_f32_16x16x32_bf16(a[0][ks], bn[ks], acc0, 0, 0, 0);
                acc1 = __builtin_amdgcn_mfma_f32_16x16x32_bf16(a[1][ks], bn[ks], acc1, 0, 0, 0);
            }
            const float bias = qkv_b[(s >> 1) * 128 + 32 * w + 16 * (s & 1) + c16];
            const int cc = 16 * (s & 1) + c16;
            if (s < 2) {
                #pragma unroll
                for (int r = 0; r < 4; ++r) {
                    qs[w][4 * g16 + r][cc]      = f2b(acc0[r] + bias);
                    qs[w][16 + 4 * g16 + r][cc] = f2b(acc1[r] + bias);
                }
            } else {
                float csum = acc0[0] + acc0[1] + acc0[2] + acc0[3]
                           + acc1[0] + acc1[1] + acc1[2] + acc1[3];
                csum += __shfl_xor(csum, 16, 64);
                csum += __shfl_xor(csum, 32, 64);
                const float meanv = csum * (1.f / 32.f) + bias;
                if (s < 4) {
                    #pragma unroll
                    for (int r = 0; r < 4; ++r) {
                        ksm[w][4 * g16 + r][cc]      = f2b(acc0[r] + bias);
                        ksm[w][16 + 4 * g16 + r][cc] = f2b(acc1[r] + bias);
                    }
                    if (g16 == 0) ksm[w][32][cc] = f2b(meanv);
                } else {
                    #pragma unroll
                    for (int r = 0; r < 4; ++r) {
                        vT[w][cc][4 * g16 + r]      = f2b(acc0[r] + bias);
                        vT[w][cc][16 + 4 * g16 + r] = f2b(acc1[r] + bias);
                    }
                    if (g16 == 0) vT[w][cc][32] = f2b(meanv);
                }
            }
        }
    }
    __syncthreads();   // drain QKV staging

    // ---- QK^T (K=32, one k-step per n-tile) ----
    f32x4 s[2][3];
    {
        bf16x8 aq0 = LD8(&qs[w][c16][g16 * 8]);
        bf16x8 aq1 = LD8(&qs[w][16 + c16][g16 * 8]);
        bf16x8 bk0 = LD8(&ksm[w][c16][g16 * 8]);
        bf16x8 bk1 = LD8(&ksm[w][16 + c16][g16 * 8]);
        const int n2 = (c16 == 0) ? 32 : 33;
        bf16x8 bk2 = LD8(&ksm[w][n2][g16 * 8]);
        s[0][0] = __builtin_amdgcn_mfma_f32_16x16x32_bf16(aq0, bk0, z4, 0, 0, 0);
        s[0][1] = __builtin_amdgcn_mfma_f32_16x16x32_bf16(aq0, bk1, z4, 0, 0, 0);
        s[0][2] = __builtin_amdgcn_mfma_f32_16x16x32_bf16(aq0, bk2, z4, 0, 0, 0);
        s[1][0] = __builtin_amdgcn_mfma_f32_16x16x32_bf16(aq1, bk0, z4, 0, 0, 0);
        s[1][1] = __builtin_amdgcn_mfma_f32_16x16x32_bf16(aq1, bk1, z4, 0, 0, 0);
        s[1][2] = __builtin_amdgcn_mfma_f32_16x16x32_bf16(aq1, bk2, z4, 0, 0, 0);
    }

    // ---- softmax with max-subtraction (overflow-proof) + gate; stage P ----
    {
        const float scale = 0.17677669529663687f;   // 32^-0.5
        const float gwh = gate_w[w], gbh = gate_b[w];
        #pragma unroll
        for (int mt = 0; mt < 2; ++mt)
            #pragma unroll
            for (int r = 0; r < 4; ++r) {
                const int i = 16 * mt + 4 * g16 + r;
                float sc[3];
                #pragma unroll
                for (int k = 0; k < 3; ++k) sc[k] = s[mt][k][r] * scale + wb[mt][r][k];
                float mx = fmaxf(fmaxf(sc[0], sc[1]), sc[2]);
                mx = fmaxf(mx, __shfl_xor(mx, 1, 64));
                mx = fmaxf(mx, __shfl_xor(mx, 2, 64));
                mx = fmaxf(mx, __shfl_xor(mx, 4, 64));
                mx = fmaxf(mx, __shfl_xor(mx, 8, 64));
                float e0 = __expf(sc[0] - mx), e1 = __expf(sc[1] - mx), e2 = __expf(sc[2] - mx);
                float sum = e0 + e1 + e2;
                sum += __shfl_xor(sum, 1, 64);
                sum += __shfl_xor(sum, 2, 64);
                sum += __shfl_xor(sum, 4, 64);
                sum += __shfl_xor(sum, 8, 64);
                const float inv = __builtin_amdgcn_rcpf(sum);
                float gt0 = (wb[mt][r][0] > -1.0e29f) ? wb[mt][r][0] * gwh + gbh : 0.f;
                float gt1 = (wb[mt][r][1] > -1.0e29f) ? wb[mt][r][1] * gwh + gbh : 0.f;
                float gt2 = (wb[mt][r][2] > -1.0e29f) ? gwh + gbh : 0.f;
                qs[w][i][c16]      = f2b(e0 * inv + gt0);
                qs[w][i][16 + c16] = f2b(e1 * inv + gt1);
                if (c16 == 0) pcol[w][i] = e2 * inv + gt2;
            }
    }
    __syncthreads();   // drain P staging

    // ---- PV (rows 0-31 via MFMA, block-node row via rank-1) -> attn-out into qs ----
    {
        bf16x8 ap0 = LD8(&qs[w][c16][g16 * 8]);
        bf16x8 ap1 = LD8(&qs[w][16 + c16][g16 * 8]);
        f32x4 o[2][2];
        #pragma unroll
        for (int nt = 0; nt < 2; ++nt) {
            bf16x8 bv = LD8(&vT[w][16 * nt + c16][g16 * 8]);
            o[0][nt] = __builtin_amdgcn_mfma_f32_16x16x32_bf16(ap0, bv, z4, 0, 0, 0);
            o[1][nt] = __builtin_amdgcn_mfma_f32_16x16x32_bf16(ap1, bv, z4, 0, 0, 0);
        }
        #pragma unroll
        for (int nt = 0; nt < 2; ++nt) {
            const float vm = b2f(vT[w][16 * nt + c16][32]);
            #pragma unroll
            for (int mt = 0; mt < 2; ++mt)
                #pragma unroll
                for (int r = 0; r < 4; ++r)
                    o[mt][nt][r] += pcol[w][16 * mt + 4 * g16 + r] * vm;
        }
        #pragma unroll
        for (int mt = 0; mt < 2; ++mt)
            #pragma unroll
            for (int nt = 0; nt < 2; ++nt)
                #pragma unroll
                for (int r = 0; r < 4; ++r)
                    qs[w][16 * mt + 4 * g16 + r][16 * nt + c16] = f2b(o[mt][nt][r]);
    }
    __syncthreads();   // all heads' attn-out ready

    // ---- projection: k-step h reads head-h buffer; wave w owns out cols [32w,32w+32) ----
    {
        bf16x8 aa[2][4];
        #pragma unroll
        for (int mt = 0; mt < 2; ++mt)
            #pragma unroll
            for (int h = 0; h < 4; ++h)
                aa[mt][h] = LD8(&qs[h][c16 + 16 * mt][g16 * 8]);
        f32x4 po[2][2];
        po[0][0] = z4; po[0][1] = z4; po[1][0] = z4; po[1][1] = z4;
        const unsigned short* wps = wp + l * 8;
        #pragma unroll
        for (int nt = 0; nt < 2; ++nt)
            #pragma unroll
            for (int h = 0; h < 4; ++h) {
                bf16x8 bw = LD8(wps + (size_t)((2 * w + nt) * 4 + h) * 512);
                po[0][nt] = __builtin_amdgcn_mfma_f32_16x16x32_bf16(aa[0][h], bw, po[0][nt], 0, 0, 0);
                po[1][nt] = __builtin_amdgcn_mfma_f32_16x16x32_bf16(aa[1][h], bw, po[1][nt], 0, 0, 0);
            }
        float* ob = out + (size_t)b * (BS * 128);
        #pragma unroll
        for (int nt = 0; nt < 2; ++nt) {
            const int col = 32 * w + 16 * nt + c16;
            const float pbv = proj_b[col];
            #pragma unroll
            for (int mt = 0; mt < 2; ++mt)
                #pragma unroll
                for (int r = 0; r < 4; ++r)
                    ob[(size_t)(16 * mt + 4 * g16 + r) * 128 + col] = po[mt][nt][r] + pbv;
        }
    }
}

extern "C" void kernel_launch(void* const* d_in, const int* in_sizes, int n_in,
                              void* d_out, int out_size, void* d_ws, size_t ws_size,
                              hipStream_t stream) {
    const float* x      = (const float*)d_in[0];
    const int*   ei     = (const int*)d_in[1];
    const float* ev     = (const float*)d_in[2];
    // d_in[3] = positions: unused by the reference output
    const float* qkv_w  = (const float*)d_in[4];
    const float* qkv_b  = (const float*)d_in[5];
    const float* proj_w = (const float*)d_in[6];
    const float* proj_b = (const float*)d_in[7];
    const float* gate_w = (const float*)d_in[8];
    const float* gate_b = (const float*)d_in[9];
    float* out = (float*)d_out;

    const int E  = in_sizes[2];
    const int N  = in_sizes[0] / 128;
    const int nb = N / BS;

    unsigned* tbl = (unsigned*)d_ws;
    size_t twords = (size_t)nb * BS * NBC;
    size_t tbytes = (twords * sizeof(unsigned) + 255) & ~(size_t)255;
    unsigned short* wqp = (unsigned short*)((char*)d_ws + tbytes);
    unsigned short* wpp = wqp + 96 * 512;

    zero_prepack_kernel<<<ZB + 256, 256, 0, stream>>>((uint4*)tbl, (int)(twords / 4),
                                                      qkv_w, proj_w, wqp, wpp);
    edge_scatter_kernel<<<((E + 3) / 4 + 255) / 256, 256, 0, stream>>>(ei, ei + E, tbl, E);
    block_attn_kernel<<<nb, 256, 0, stream>>>(x, tbl, ev, wqp, wpp, qkv_b, proj_b,
                                              gate_w, gate_b, out);
}

// Round 6
// 259.059 us; speedup vs baseline: 1.1931x; 1.0452x over previous
//
#include <hip/hip_runtime.h>
#include <hip/hip_bf16.h>

#define BS 32
#define NBC 33

typedef unsigned long long ull;
typedef __attribute__((ext_vector_type(8))) __bf16 bf16x8;
typedef __attribute__((ext_vector_type(4))) float f32x4;
typedef __attribute__((ext_vector_type(4))) unsigned short us4;

__device__ __forceinline__ unsigned short f2b(float f) {
    __hip_bfloat16 h = __float2bfloat16(f);
    return *reinterpret_cast<unsigned short*>(&h);
}
__device__ __forceinline__ float b2f(unsigned short u) {
    union { unsigned int i; float f; } x; x.i = ((unsigned int)u) << 16; return x.f;
}
#define LD8(p) (*reinterpret_cast<const bf16x8*>(p))

// ---- fused: zero the ull table (blocks 0..ZB-1) + repack weights (blocks ZB..) ----
#define ZB 2048
__global__ void zero_prepack_kernel(uint4* __restrict__ tbl4, int n4,
                                    const float* __restrict__ qkv_w,
                                    const float* __restrict__ proj_w,
                                    unsigned short* __restrict__ wq,
                                    unsigned short* __restrict__ wp) {
    if (blockIdx.x < ZB) {
        int stride = ZB * 256;
        for (int i = blockIdx.x * 256 + threadIdx.x; i < n4; i += stride)
            tbl4[i] = make_uint4(0u, 0u, 0u, 0u);
    } else {
        int tid = (blockIdx.x - ZB) * 256 + threadIdx.x;   // 0..65535
        int f = tid >> 9, lane = (tid >> 3) & 63, j = tid & 7;
        int ks = f & 3;
        int kk = ks * 32 + (lane >> 4) * 8 + j;
        int nn = lane & 15;
        if (f < 96) {
            int t = f >> 2;                 // 0..23
            int w = t / 6, s = t % 6;
            int g = (s < 2) ? (2 * w + s) : (s < 4) ? (8 + 2 * w + (s - 2)) : (16 + 2 * w + (s - 4));
            wq[tid] = f2b(qkv_w[kk * 384 + g * 16 + nn]);
        } else {
            int f2 = f - 96;                // proj frag = nt_global*4+ks
            wp[f2 * 512 + lane * 8 + j] = f2b(proj_w[kk * 128 + (f2 >> 2) * 16 + nn]);
        }
    }
}

// ---- pass 1: last-edge-wins scatter; key = (edge_id+1)<<32 | float_bits(value) ----
// atomicMax picks the highest edge id (numpy last-write-wins); value rides in low bits;
// word==0 doubles as "no edge" (mask 0). ids differ => low bits never decide.
__global__ void edge_scatter_kernel(const int* __restrict__ rows,
                                    const int* __restrict__ cols,
                                    const float* __restrict__ vals,
                                    ull* __restrict__ tbl, int E) {
    int base = (blockIdx.x * 256 + threadIdx.x) * 4;
    if (base >= E) return;
    if (base + 4 <= E) {
        int4 r4 = *reinterpret_cast<const int4*>(rows + base);
        int4 c4 = *reinterpret_cast<const int4*>(cols + base);
        float4 v4 = *reinterpret_cast<const float4*>(vals + base);
        int rr[4] = {r4.x, r4.y, r4.z, r4.w};
        int cc[4] = {c4.x, c4.y, c4.z, c4.w};
        float vv[4] = {v4.x, v4.y, v4.z, v4.w};
        #pragma unroll
        for (int k = 0; k < 4; ++k) {
            int r = rr[k], c = cc[k];
            if ((r >> 5) == (c >> 5) && r != c) {
                ull key = ((ull)(unsigned)(base + k + 1) << 32) | (ull)__float_as_uint(vv[k]);
                atomicMax(&tbl[((size_t)(r >> 5) * BS + (r & 31)) * NBC + (c & 31)], key);
            }
        }
    } else {
        for (int e = base; e < E && e < base + 4; ++e) {
            int r = rows[e], c = cols[e];
            if ((r >> 5) == (c >> 5) && r != c) {
                ull key = ((ull)(unsigned)(e + 1) << 32) | (ull)__float_as_uint(vals[e]);
                atomicMax(&tbl[((size_t)(r >> 5) * BS + (r & 31)) * NBC + (c & 31)], key);
            }
        }
    }
}

// ---- main fused kernel: one 4-wave WG per block; wave w owns head w end-to-end ----
__global__ __launch_bounds__(256)
void block_attn_kernel(const float* __restrict__ x,
                       const ull* __restrict__ tbl,
                       const unsigned short* __restrict__ wq,
                       const unsigned short* __restrict__ wp,
                       const float* __restrict__ qkv_b,
                       const float* __restrict__ proj_b,
                       const float* __restrict__ gate_w,
                       const float* __restrict__ gate_b,
                       float* __restrict__ out) {
    // 31872 B total -> 5 WGs/CU. xs (x staging) overlays the vT region: x is
    // consumed into A-fragment registers before any vT write (barrier-enforced).
    __shared__ __align__(16) unsigned char smem[31872];
    unsigned short (*qs)[32][40]  = (unsigned short (*)[32][40])(smem);           // 10240 B
    unsigned short (*ksm)[34][40] = (unsigned short (*)[34][40])(smem + 10240);   // 10880 B
    unsigned short (*vT)[32][40]  = (unsigned short (*)[32][40])(smem + 21120);   // 10240 B
    float (*pcol)[32]             = (float (*)[32])(smem + 31360);                //   512 B
    unsigned short (*xs)[136]     = (unsigned short (*)[136])(smem + 21120);      //  8704 B (overlay)

    const int b = blockIdx.x, t = threadIdx.x;
    const int w = t >> 6, l = t & 63, g16 = l >> 4, c16 = l & 15;
    const f32x4 z4 = {0.f, 0.f, 0.f, 0.f};
    const float NEG = -1.0e30f;

    // ---- phase 0: stage x block (coalesced float4 -> bf16 LDS) ----
    const float* xb = x + (size_t)b * (BS * 128);
    #pragma unroll
    for (int it = 0; it < 4; ++it) {
        int idx = (t + it * 256) * 4;
        float4 v = *reinterpret_cast<const float4*>(xb + idx);
        us4 u; u.x = f2b(v.x); u.y = f2b(v.y); u.z = f2b(v.z); u.w = f2b(v.w);
        *reinterpret_cast<us4*>(&xs[idx >> 7][idx & 127]) = u;
    }
    if (l < 32) ksm[w][33][l] = 0;   // zero pad row (wave-private use)

    // ---- edge bias wb per score slot from packed table (value embedded, no gather) ----
    // slot 0: j=c16; slot 1: j=16+c16; slot 2: block-node col (real only at c16==0)
    float wb[2][4][3];
    {
        const ull* tb = tbl + (size_t)b * (BS * NBC);
        #pragma unroll
        for (int mt = 0; mt < 2; ++mt)
            #pragma unroll
            for (int r = 0; r < 4; ++r) {
                const int i = 16 * mt + 4 * g16 + r;
                #pragma unroll
                for (int nt = 0; nt < 2; ++nt) {
                    const int j = 16 * nt + c16;
                    const ull wv = tb[i * NBC + j];
                    wb[mt][r][nt] = (j == i) ? 1.f
                                   : (wv ? __uint_as_float((unsigned)(wv & 0xffffffffu)) : NEG);
                }
                wb[mt][r][2] = (c16 == 0) ? 1.f : NEG;
            }
    }
    __syncthreads();   // x staged

    // ---- A-fragments from LDS ----
    bf16x8 a[2][4];
    #pragma unroll
    for (int mt = 0; mt < 2; ++mt)
        #pragma unroll
        for (int ks = 0; ks < 4; ++ks)
            a[mt][ks] = LD8(&xs[c16 + 16 * mt][ks * 32 + g16 * 8]);
    __syncthreads();   // xs consumed; overlay region may now be written as vT

    // ---- QKV for head w: 6 n-tiles (q0,q1,k0,k1,v0,v1), K=128 ----
    {
        const unsigned short* wqs = wq + (size_t)(w * 24) * 512 + l * 8;
        #pragma unroll
        for (int s = 0; s < 6; ++s) {
            bf16x8 bn[4];
            #pragma unroll
            for (int ks = 0; ks < 4; ++ks) bn[ks] = LD8(wqs + (s * 4 + ks) * 512);
            f32x4 acc0 = z4, acc1 = z4;
            #pragma unroll
            for (int ks = 0; ks < 4; ++ks) {
                acc0 = __builtin_amdgcn_mfma_f32_16x16x32_bf16(a[0][ks], bn[ks], acc0, 0, 0, 0);
                acc1 = __builtin_amdgcn_mfma_f32_16x16x32_bf16(a[1][ks], bn[ks], acc1, 0, 0, 0);
            }
            const float bias = qkv_b[(s >> 1) * 128 + 32 * w + 16 * (s & 1) + c16];
            const int cc = 16 * (s & 1) + c16;
            if (s < 2) {
                #pragma unroll
                for (int r = 0; r < 4; ++r) {
                    qs[w][4 * g16 + r][cc]      = f2b(acc0[r] + bias);
                    qs[w][16 + 4 * g16 + r][cc] = f2b(acc1[r] + bias);
                }
            } else {
                float csum = acc0[0] + acc0[1] + acc0[2] + acc0[3]
                           + acc1[0] + acc1[1] + acc1[2] + acc1[3];
                csum += __shfl_xor(csum, 16, 64);
                csum += __shfl_xor(csum, 32, 64);
                const float meanv = csum * (1.f / 32.f) + bias;
                if (s < 4) {
                    #pragma unroll
                    for (int r = 0; r < 4; ++r) {
                        ksm[w][4 * g16 + r][cc]      = f2b(acc0[r] + bias);
                        ksm[w][16 + 4 * g16 + r][cc] = f2b(acc1[r] + bias);
                    }
                    if (g16 == 0) ksm[w][32][cc] = f2b(meanv);
                } else {
                    #pragma unroll
                    for (int r = 0; r < 4; ++r) {
                        vT[w][cc][4 * g16 + r]      = f2b(acc0[r] + bias);
                        vT[w][cc][16 + 4 * g16 + r] = f2b(acc1[r] + bias);
                    }
                    if (g16 == 0) vT[w][cc][32] = f2b(meanv);
                }
            }
        }
    }
    __syncthreads();   // drain QKV staging

    // ---- QK^T (K=32, one k-step per n-tile) ----
    f32x4 s[2][3];
    {
        bf16x8 aq0 = LD8(&qs[w][c16][g16 * 8]);
        bf16x8 aq1 = LD8(&qs[w][16 + c16][g16 * 8]);
        bf16x8 bk0 = LD8(&ksm[w][c16][g16 * 8]);
        bf16x8 bk1 = LD8(&ksm[w][16 + c16][g16 * 8]);
        const int n2 = (c16 == 0) ? 32 : 33;
        bf16x8 bk2 = LD8(&ksm[w][n2][g16 * 8]);
        s[0][0] = __builtin_amdgcn_mfma_f32_16x16x32_bf16(aq0, bk0, z4, 0, 0, 0);
        s[0][1] = __builtin_amdgcn_mfma_f32_16x16x32_bf16(aq0, bk1, z4, 0, 0, 0);
        s[0][2] = __builtin_amdgcn_mfma_f32_16x16x32_bf16(aq0, bk2, z4, 0, 0, 0);
        s[1][0] = __builtin_amdgcn_mfma_f32_16x16x32_bf16(aq1, bk0, z4, 0, 0, 0);
        s[1][1] = __builtin_amdgcn_mfma_f32_16x16x32_bf16(aq1, bk1, z4, 0, 0, 0);
        s[1][2] = __builtin_amdgcn_mfma_f32_16x16x32_bf16(aq1, bk2, z4, 0, 0, 0);
    }

    // ---- softmax with max-subtraction (overflow-proof) + gate; stage P ----
    {
        const float scale = 0.17677669529663687f;   // 32^-0.5
        const float gwh = gate_w[w], gbh = gate_b[w];
        #pragma unroll
        for (int mt = 0; mt < 2; ++mt)
            #pragma unroll
            for (int r = 0; r < 4; ++r) {
                const int i = 16 * mt + 4 * g16 + r;
                float sc[3];
                #pragma unroll
                for (int k = 0; k < 3; ++k) sc[k] = s[mt][k][r] * scale + wb[mt][r][k];
                float mx = fmaxf(fmaxf(sc[0], sc[1]), sc[2]);
                mx = fmaxf(mx, __shfl_xor(mx, 1, 64));
                mx = fmaxf(mx, __shfl_xor(mx, 2, 64));
                mx = fmaxf(mx, __shfl_xor(mx, 4, 64));
                mx = fmaxf(mx, __shfl_xor(mx, 8, 64));
                float e0 = __expf(sc[0] - mx), e1 = __expf(sc[1] - mx), e2 = __expf(sc[2] - mx);
                float sum = e0 + e1 + e2;
                sum += __shfl_xor(sum, 1, 64);
                sum += __shfl_xor(sum, 2, 64);
                sum += __shfl_xor(sum, 4, 64);
                sum += __shfl_xor(sum, 8, 64);
                const float inv = __builtin_amdgcn_rcpf(sum);
                float gt0 = (wb[mt][r][0] > -1.0e29f) ? wb[mt][r][0] * gwh + gbh : 0.f;
                float gt1 = (wb[mt][r][1] > -1.0e29f) ? wb[mt][r][1] * gwh + gbh : 0.f;
                float gt2 = (wb[mt][r][2] > -1.0e29f) ? gwh + gbh : 0.f;
                qs[w][i][c16]      = f2b(e0 * inv + gt0);
                qs[w][i][16 + c16] = f2b(e1 * inv + gt1);
                if (c16 == 0) pcol[w][i] = e2 * inv + gt2;
            }
    }
    __syncthreads();   // drain P staging

    // ---- PV (rows 0-31 via MFMA, block-node row via rank-1) -> attn-out into qs ----
    {
        bf16x8 ap0 = LD8(&qs[w][c16][g16 * 8]);
        bf16x8 ap1 = LD8(&qs[w][16 + c16][g16 * 8]);
        f32x4 o[2][2];
        #pragma unroll
        for (int nt = 0; nt < 2; ++nt) {
            bf16x8 bv = LD8(&vT[w][16 * nt + c16][g16 * 8]);
            o[0][nt] = __builtin_amdgcn_mfma_f32_16x16x32_bf16(ap0, bv, z4, 0, 0, 0);
            o[1][nt] = __builtin_amdgcn_mfma_f32_16x16x32_bf16(ap1, bv, z4, 0, 0, 0);
        }
        #pragma unroll
        for (int nt = 0; nt < 2; ++nt) {
            const float vm = b2f(vT[w][16 * nt + c16][32]);
            #pragma unroll
            for (int mt = 0; mt < 2; ++mt)
                #pragma unroll
                for (int r = 0; r < 4; ++r)
                    o[mt][nt][r] += pcol[w][16 * mt + 4 * g16 + r] * vm;
        }
        #pragma unroll
        for (int mt = 0; mt < 2; ++mt)
            #pragma unroll
            for (int nt = 0; nt < 2; ++nt)
                #pragma unroll
                for (int r = 0; r < 4; ++r)
                    qs[w][16 * mt + 4 * g16 + r][16 * nt + c16] = f2b(o[mt][nt][r]);
    }
    __syncthreads();   // all heads' attn-out ready

    // ---- projection: k-step h reads head-h buffer; wave w owns out cols [32w,32w+32) ----
    {
        bf16x8 aa[2][4];
        #pragma unroll
        for (int mt = 0; mt < 2; ++mt)
            #pragma unroll
            for (int h = 0; h < 4; ++h)
                aa[mt][h] = LD8(&qs[h][c16 + 16 * mt][g16 * 8]);
        f32x4 po[2][2];
        po[0][0] = z4; po[0][1] = z4; po[1][0] = z4; po[1][1] = z4;
        const unsigned short* wps = wp + l * 8;
        #pragma unroll
        for (int nt = 0; nt < 2; ++nt)
            #pragma unroll
            for (int h = 0; h < 4; ++h) {
                bf16x8 bw = LD8(wps + (size_t)((2 * w + nt) * 4 + h) * 512);
                po[0][nt] = __builtin_amdgcn_mfma_f32_16x16x32_bf16(aa[0][h], bw, po[0][nt], 0, 0, 0);
                po[1][nt] = __builtin_amdgcn_mfma_f32_16x16x32_bf16(aa[1][h], bw, po[1][nt], 0, 0, 0);
            }
        float* ob = out + (size_t)b * (BS * 128);
        #pragma unroll
        for (int nt = 0; nt < 2; ++nt) {
            const int col = 32 * w + 16 * nt + c16;
            const float pbv = proj_b[col];
            #pragma unroll
            for (int mt = 0; mt < 2; ++mt)
                #pragma unroll
                for (int r = 0; r < 4; ++r)
                    ob[(size_t)(16 * mt + 4 * g16 + r) * 128 + col] = po[mt][nt][r] + pbv;
        }
    }
}

extern "C" void kernel_launch(void* const* d_in, const int* in_sizes, int n_in,
                              void* d_out, int out_size, void* d_ws, size_t ws_size,
                              hipStream_t stream) {
    const float* x      = (const float*)d_in[0];
    const int*   ei     = (const int*)d_in[1];
    const float* ev     = (const float*)d_in[2];
    // d_in[3] = positions: unused by the reference output
    const float* qkv_w  = (const float*)d_in[4];
    const float* qkv_b  = (const float*)d_in[5];
    const float* proj_w = (const float*)d_in[6];
    const float* proj_b = (const float*)d_in[7];
    const float* gate_w = (const float*)d_in[8];
    const float* gate_b = (const float*)d_in[9];
    float* out = (float*)d_out;

    const int E  = in_sizes[2];
    const int N  = in_sizes[0] / 128;
    const int nb = N / BS;

    ull* tbl = (ull*)d_ws;
    size_t twords = (size_t)nb * BS * NBC;              // ull count
    size_t tbytes = (twords * sizeof(ull) + 255) & ~(size_t)255;
    unsigned short* wqp = (unsigned short*)((char*)d_ws + tbytes);
    unsigned short* wpp = wqp + 96 * 512;

    zero_prepack_kernel<<<ZB + 256, 256, 0, stream>>>((uint4*)tbl,
                                                      (int)(twords * sizeof(ull) / 16),
                                                      qkv_w, proj_w, wqp, wpp);
    edge_scatter_kernel<<<((E + 3) / 4 + 255) / 256, 256, 0, stream>>>(ei, ei + E, ev, tbl, E);
    block_attn_kernel<<<nb, 256, 0, stream>>>(x, tbl, wqp, wpp, qkv_b, proj_b,
                                              gate_w, gate_b, out);
}